// Round 13
// baseline (160.442 us; speedup 1.0000x reference)
//
#include <hip/hip_runtime.h>
#include <math.h>

#define DIM 64
#define FDIM 256   // DIM * H (H=4)
#define DEFER_THR 4.0f

typedef _Float16 h2 __attribute__((ext_vector_type(2)));

// ---------------- Stage 1: ft = f16(h_v @ W_fc^T + b_fc)  -> [N, 256] ----------------
__global__ __launch_bounds__(256) void fc_kernel(const float* __restrict__ h,
                                                 const float* __restrict__ W,
                                                 const float* __restrict__ b,
                                                 _Float16* __restrict__ ft, int N)
{
    int t = threadIdx.x;              // output column 0..255
    float w[DIM];
#pragma unroll
    for (int j = 0; j < DIM / 4; ++j) {
        float4 v = *(const float4*)(W + (size_t)t * DIM + j * 4);
        w[4 * j + 0] = v.x; w[4 * j + 1] = v.y;
        w[4 * j + 2] = v.z; w[4 * j + 3] = v.w;
    }
    float bt = b[t];
    for (int r = blockIdx.x; r < N; r += gridDim.x) {
        const float4* h4 = (const float4*)(h + (size_t)r * DIM);
        float acc = bt;
#pragma unroll
        for (int j = 0; j < DIM / 4; ++j) {
            float4 hv = h4[j];       // uniform address across the wave
            acc = fmaf(hv.x, w[4 * j + 0], acc);
            acc = fmaf(hv.y, w[4 * j + 1], acc);
            acc = fmaf(hv.z, w[4 * j + 2], acc);
            acc = fmaf(hv.w, w[4 * j + 3], acc);
        }
        ft[(size_t)r * FDIM + t] = (_Float16)acc;
    }
}

// ---------------- Counting sort of edges by dst ----------------
// hist + per-edge rank: atomic return value IS the rank within the dst segment.
__global__ void hist_rank_kernel(const int* __restrict__ dst, int* __restrict__ cnt,
                                 int* __restrict__ rank, int E)
{
    int i = blockIdx.x * blockDim.x + threadIdx.x;
    if (i < E) rank[i] = atomicAdd(&cnt[dst[i]], 1);
}

__global__ __launch_bounds__(256) void scanA_kernel(const int* __restrict__ cnt,
                                                    int* __restrict__ off,
                                                    int* __restrict__ bsum, int N)
{
    __shared__ int sh[256];
    int t = threadIdx.x;
    int i = blockIdx.x * 256 + t;
    int v = (i < N) ? cnt[i] : 0;
    sh[t] = v;
    __syncthreads();
#pragma unroll
    for (int o = 1; o < 256; o <<= 1) {
        int x = (t >= o) ? sh[t - o] : 0;
        __syncthreads();
        sh[t] += x;
        __syncthreads();
    }
    if (i < N) off[i] = sh[t] - v;          // local exclusive
    if (t == 255) bsum[blockIdx.x] = sh[255];
}

__global__ __launch_bounds__(256) void scanB_kernel(int* __restrict__ bsum, int nb)
{
    __shared__ int sh[256];
    int t = threadIdx.x;
    int carry = 0;
    for (int base = 0; base < nb; base += 256) {
        int i = base + t;
        int v = (i < nb) ? bsum[i] : 0;
        sh[t] = v;
        __syncthreads();
#pragma unroll
        for (int o = 1; o < 256; o <<= 1) {
            int x = (t >= o) ? sh[t - o] : 0;
            __syncthreads();
            sh[t] += x;
            __syncthreads();
        }
        if (i < nb) bsum[i] = carry + sh[t] - v;   // exclusive
        int tot = sh[255];
        __syncthreads();
        carry += tot;
    }
}

// Atomic-free scatter: pos = (off[d] + bsum[d>>8]) + rank.
__global__ void scatter_kernel(const int* __restrict__ src, const int* __restrict__ dst,
                               const int* __restrict__ off, const int* __restrict__ bsum,
                               const int* __restrict__ rank,
                               int* __restrict__ ssrc, int E)
{
    int i = blockIdx.x * blockDim.x + threadIdx.x;
    if (i < E) {
        int d = dst[i];
        ssrc[off[d] + bsum[d >> 8] + rank[i]] = src[i];
    }
}

// ---------------- Fused: score + edge-softmax + weighted sum + head-max ----------------
// One wave per node. 8 edges/iter (2 per quarter), independent per-quarter online softmax,
// 1 pack prefetched ahead. Accumulation via v_fma_mix (f16 src, f32 acc).
// Epilogue: LDS transpose -> quarter-sum + head-max -> coalesced store.
__global__ __launch_bounds__(256) void agg_kernel(const _Float16* __restrict__ ft,
                                                  const int* __restrict__ off,
                                                  const int* __restrict__ bsum,
                                                  const int* __restrict__ ssrc,
                                                  const float* __restrict__ Wpi,
                                                  float* __restrict__ out, int N, int E)
{
    __shared__ float xb[4][1280];     // per-wave 64 lanes * 20 words (padded 16->20)
    int wid = (blockIdx.x * blockDim.x + threadIdx.x) >> 6;
    int wv  = threadIdx.x >> 6;       // wave within block
    int lane = threadIdx.x & 63;
    if (wid >= N) return;
    int q  = lane >> 4;
    int ql = lane & 15;

    // fdwh[k] = f16( ft[wid][16*ql+2k..2k+1] * Wpi[...] )
    h2 fdwh[8];
    {
        const float* wp = Wpi + ql * 16;
        const _Float16* drow = ft + (size_t)wid * FDIM + ql * 16;
        uint4 a = *(const uint4*)(drow);
        uint4 b = *(const uint4*)(drow + 8);
        const h2* da = (const h2*)&a;
        const h2* db = (const h2*)&b;
#pragma unroll
        for (int j = 0; j < 4; ++j) {
            h2 v = da[j], u = db[j];
            fdwh[j].x     = (_Float16)((float)v.x * wp[2 * j + 0]);
            fdwh[j].y     = (_Float16)((float)v.y * wp[2 * j + 1]);
            fdwh[4 + j].x = (_Float16)((float)u.x * wp[8 + 2 * j + 0]);
            fdwh[4 + j].y = (_Float16)((float)u.y * wp[8 + 2 * j + 1]);
        }
    }

    int e0 = off[wid] + bsum[wid >> 8];
    int e1 = (wid + 1 < N) ? (off[wid + 1] + bsum[(wid + 1) >> 8]) : E;
    float mq = -INFINITY, lq = 0.f;
    float acc[16];
#pragma unroll
    for (int j = 0; j < 16; ++j) acc[j] = 0.f;

    auto LOAD8 = [&](uint4& a1, uint4& b1, uint4& a2, uint4& b2,
                     bool& v1, bool& v2, int bse) {
        int lo = bse + q, hi = bse + q + 4;
        v1 = lo < e1; v2 = hi < e1;
        int s1 = ssrc[v1 ? lo : e0];
        int s2 = ssrc[v2 ? hi : e0];
        const _Float16* r1 = ft + (size_t)s1 * FDIM + ql * 16;
        const _Float16* r2 = ft + (size_t)s2 * FDIM + ql * 16;
        a1 = *(const uint4*)(r1);
        b1 = *(const uint4*)(r1 + 8);
        a2 = *(const uint4*)(r2);
        b2 = *(const uint4*)(r2 + 8);
    };
    auto COMP8 = [&](uint4 a1, uint4 b1, uint4 a2, uint4 b2, bool v1, bool v2) {
        const h2* fa1 = (const h2*)&a1; const h2* fb1 = (const h2*)&b1;
        const h2* fa2 = (const h2*)&a2; const h2* fb2 = (const h2*)&b2;
        float p1 = 0.f, p2 = 0.f;
#pragma unroll
        for (int j = 0; j < 4; ++j) {
            p1 = __builtin_amdgcn_fdot2(fa1[j], fdwh[j], p1, false);
            p2 = __builtin_amdgcn_fdot2(fa2[j], fdwh[j], p2, false);
        }
#pragma unroll
        for (int j = 0; j < 4; ++j) {
            p1 = __builtin_amdgcn_fdot2(fb1[j], fdwh[4 + j], p1, false);
            p2 = __builtin_amdgcn_fdot2(fb2[j], fdwh[4 + j], p2, false);
        }
        p1 += __shfl_xor(p1, 1, 64);  p2 += __shfl_xor(p2, 1, 64);
        p1 += __shfl_xor(p1, 2, 64);  p2 += __shfl_xor(p2, 2, 64);
        p1 += __shfl_xor(p1, 4, 64);  p2 += __shfl_xor(p2, 4, 64);
        p1 += __shfl_xor(p1, 8, 64);  p2 += __shfl_xor(p2, 8, 64);
        float s1 = p1 > 0.f ? p1 : 0.2f * p1;     // LeakyReLU(0.2)
        float s2 = p2 > 0.f ? p2 : 0.2f * p2;
        if (!v1) s1 = -INFINITY;
        if (!v2) s2 = -INFINITY;
        float smax = fmaxf(s1, s2);
        if (smax > mq + DEFER_THR) {              // first valid edge: -inf -> taken
            float sc = __expf(mq - smax);         // first: exp(-inf)=0
            lq *= sc;
#pragma unroll
            for (int j = 0; j < 16; ++j) acc[j] *= sc;
            mq = smax;
        }
        float pe1 = v1 ? __expf(s1 - mq) : 0.f;   // bounded by e^THR
        float pe2 = v2 ? __expf(s2 - mq) : 0.f;
        lq += pe1 + pe2;
        // v_fma_mix_f32: fpext(f16)*f32 + f32 in one instruction
#pragma unroll
        for (int j = 0; j < 4; ++j) {
            acc[2 * j + 0] = fmaf((float)fa1[j].x, pe1, acc[2 * j + 0]);
            acc[2 * j + 1] = fmaf((float)fa1[j].y, pe1, acc[2 * j + 1]);
            acc[8 + 2 * j + 0] = fmaf((float)fb1[j].x, pe1, acc[8 + 2 * j + 0]);
            acc[8 + 2 * j + 1] = fmaf((float)fb1[j].y, pe1, acc[8 + 2 * j + 1]);
        }
#pragma unroll
        for (int j = 0; j < 4; ++j) {
            acc[2 * j + 0] = fmaf((float)fa2[j].x, pe2, acc[2 * j + 0]);
            acc[2 * j + 1] = fmaf((float)fa2[j].y, pe2, acc[2 * j + 1]);
            acc[8 + 2 * j + 0] = fmaf((float)fb2[j].x, pe2, acc[8 + 2 * j + 0]);
            acc[8 + 2 * j + 1] = fmaf((float)fb2[j].y, pe2, acc[8 + 2 * j + 1]);
        }
    };

    if (e0 < e1) {
        uint4 Aa1, Ab1, Aa2, Ab2, Ba1, Bb1, Ba2, Bb2;
        bool Av1, Av2, Bv1, Bv2;
        int base = e0;
        LOAD8(Aa1, Ab1, Aa2, Ab2, Av1, Av2, base);
        while (true) {
            int nxt = base + 8;
            bool more = nxt < e1;
            if (more) LOAD8(Ba1, Bb1, Ba2, Bb2, Bv1, Bv2, nxt);
            COMP8(Aa1, Ab1, Aa2, Ab2, Av1, Av2);
            if (!more) break;
            base = nxt;
            nxt = base + 8;
            more = nxt < e1;
            if (more) LOAD8(Aa1, Ab1, Aa2, Ab2, Av1, Av2, nxt);
            COMP8(Ba1, Bb1, Ba2, Bb2, Bv1, Bv2);
            if (!more) break;
            base = nxt;
        }
    }

    // ---- merge quarter states (4 shuffles total) ----
    float mstar = fmaxf(mq, __shfl_xor(mq, 16, 64));
    mstar = fmaxf(mstar, __shfl_xor(mstar, 32, 64));
    float sc = (lq > 0.f) ? __expf(mq - mstar) : 0.f;
    float lt = lq * sc;
    lt += __shfl_xor(lt, 16, 64);
    lt += __shfl_xor(lt, 32, 64);
    float inv = (lt > 0.f) ? 1.f / lt : 0.f;

    // ---- LDS transpose epilogue ----
    {
        float* wp = &xb[wv][(unsigned)lane * 20];
#pragma unroll
        for (int k = 0; k < 4; ++k) {
            *(float4*)(wp + 4 * k) = make_float4(acc[4 * k] * sc, acc[4 * k + 1] * sc,
                                                 acc[4 * k + 2] * sc, acc[4 * k + 3] * sc);
        }
    }
    asm volatile("s_waitcnt lgkmcnt(0)" ::: "memory");
    // lane L -> output dim d=L: col=d>>4, jp=d&15;
    // sum over q of V[q][col+4h][jp], then max over heads h
    {
        int col = lane >> 4, jp = lane & 15;
        float A[4];
#pragma unroll
        for (int h = 0; h < 4; ++h) {
            int rowb = (col + 4 * h) * 20 + jp;
            float v0 = xb[wv][rowb];
            float v1 = xb[wv][rowb + 16 * 20];
            float v2 = xb[wv][rowb + 32 * 20];
            float v3 = xb[wv][rowb + 48 * 20];
            A[h] = (v0 + v1) + (v2 + v3);
        }
        float r = fmaxf(fmaxf(A[0], A[1]), fmaxf(A[2], A[3])) * inv;
        out[(size_t)wid * DIM + lane] = r;
    }
}

extern "C" void kernel_launch(void* const* d_in, const int* in_sizes, int n_in,
                              void* d_out, int out_size, void* d_ws, size_t ws_size,
                              hipStream_t stream)
{
    const float* h_v  = (const float*)d_in[0];
    const int*   src  = (const int*)d_in[1];
    const int*   dst  = (const int*)d_in[2];
    const float* W_fc = (const float*)d_in[3];
    const float* b_fc = (const float*)d_in[4];
    const float* W_pi = (const float*)d_in[5];
    float* out = (float*)d_out;

    int N = in_sizes[0] / DIM;
    int E = in_sizes[1];

    // workspace layout
    _Float16* ft = (_Float16*)d_ws;                        // N*256*2 = 25.6 MB
    size_t ftB = (((size_t)N * FDIM * 2) + 255) & ~(size_t)255;
    char*  p    = (char*)d_ws + ftB;
    int*   cnt  = (int*)(p);                               // N          (@0)
    int*   off  = (int*)(p + 256 * 1024);                  // N          (@256KB)
    int*   bsum = (int*)(p + 512 * 1024);                  // ceil(N/256)(@512KB)
    int*   rank = (int*)(p + 768 * 1024);                  // E          (@768KB)
    int*   ssrc = (int*)(p + 768 * 1024 + (((size_t)E * 4 + 255) & ~(size_t)255)); // E

    int nb = (N + 255) / 256;
    int eb = (E + 255) / 256;            // 1 edge per thread
    fc_kernel<<<1024, 256, 0, stream>>>(h_v, W_fc, b_fc, ft, N);
    hipMemsetAsync(cnt, 0, (size_t)N * sizeof(int), stream);
    hist_rank_kernel<<<eb, 256, 0, stream>>>(dst, cnt, rank, E);
    scanA_kernel<<<nb, 256, 0, stream>>>(cnt, off, bsum, N);
    scanB_kernel<<<1, 256, 0, stream>>>(bsum, nb);
    scatter_kernel<<<eb, 256, 0, stream>>>(src, dst, off, bsum, rank, ssrc, E);
    int blocks = (N * 64 + 255) / 256;   // one 64-lane wave per node
    agg_kernel<<<blocks, 256, 0, stream>>>(ft, off, bsum, ssrc, W_pi, out, N, E);
}